// Round 12
// baseline (99.109 us; speedup 1.0000x reference)
//
#include <hip/hip_runtime.h>
#include <stdint.h>

#define NBOX 25200
#define BATCH 32
#define TOPK 1024
#define MAXDET 300
#define BINCAP 2048
#define SEGCAP 256
#define NSEG 64
#define CONF_T 0.25f
#define IOU_T 0.45f
#define KEY_BIAS 0x3E800001u   // conf > 0.25 => bits(conf) >= 0x3E800001; key in [0, 0x00FFFFFF]

// ---- workspace layout (bytes) ----
#define SEGS_OFF   0u            // [32][64][256] u64  = 4194304
#define SEGCNT_OFF 4194304u      // [32][64] u32       = 8192
#define GHIST_OFF  4202496u      // [32][16][256] u32  = 524288
#define SORTED_OFF 4726784u      // [32][1024] u64     = 262144
#define SBOX_OFF   4988928u      // [32][1024] float4  = 524288
#define SAREA_OFF  5513216u      // [32][1024] f32     = 131072
#define WS_NEED    5644288u

__device__ __forceinline__ float iou_of(float4 a, float ar_a, float4 bq, float ar_b) {
    float xx1 = fmaxf(a.x, bq.x);
    float yy1 = fmaxf(a.y, bq.y);
    float xx2 = fminf(a.z, bq.z);
    float yy2 = fminf(a.w, bq.w);
    float iw = fmaxf(xx2 - xx1, 0.0f);
    float ih = fmaxf(yy2 - yy1, 0.0f);
    float inter = iw * ih;
    return inter / (ar_a + ar_b - inter + 1e-9f);
}

// ================= K1: per-wave segment extract (512 blocks, 2/CU; no zeroing, no global atomics) ===
__global__ __launch_bounds__(256) void k1_extract(const float* __restrict__ x,
                                                  unsigned long long* __restrict__ segs,
                                                  unsigned* __restrict__ segcnt,
                                                  unsigned* __restrict__ ghist) {
    const int blk = blockIdx.x;          // 512 = 32 batches * 16 slices
    const int b = blk >> 4;
    const int sl = blk & 15;
    const int tid = threadIdx.x;
    const int lane = tid & 63;
    const int wv = tid >> 6;
    const int seg = sl * 4 + wv;         // 0..63
    const float* __restrict__ xb = x + (size_t)b * NBOX * 6;
    unsigned long long* __restrict__ sb = segs + ((size_t)b * NSEG + seg) * SEGCAP;

    __shared__ unsigned hist[256];
    hist[tid] = 0;
    __syncthreads();

    const int n0 = (seg * NBOX) / NSEG;
    const int n1 = ((seg + 1) * NBOX) / NSEG;
    unsigned base = 0;
    const unsigned long long lmask = (1ull << lane) - 1ull;
    #pragma unroll 2
    for (int n = n0 + lane; n < n1; n += 64) {
        float2 oc = *reinterpret_cast<const float2*>(xb + n * 6 + 4);
        float conf = oc.x * oc.y;
        bool take = conf > CONF_T;
        unsigned key = 0;
        if (take) {
            key = __float_as_uint(conf) - KEY_BIAS;
            atomicAdd(&hist[min(key >> 16, 255u)], 1u);
        }
        unsigned long long m = __ballot(take);
        if (take) {
            unsigned pos = base + (unsigned)__popcll(m & lmask);
            if (pos < SEGCAP)
                sb[pos] = ((unsigned long long)key << 32) | (unsigned)(~(unsigned)n);
        }
        base += (unsigned)__popcll(m);
    }
    if (lane == 0) segcnt[b * NSEG + seg] = min(base, (unsigned)SEGCAP);
    __syncthreads();
    ghist[(size_t)blk * 256 + tid] = hist[tid];
}

// ================= K2: selbin + LDS bucket-scatter + within-bin rank + gather =================
__global__ __launch_bounds__(1024) void k2_sort(const float* __restrict__ x,
                                                const unsigned long long* __restrict__ segs,
                                                const unsigned* __restrict__ segcnt,
                                                const unsigned* __restrict__ ghist,
                                                unsigned long long* __restrict__ sorted_g,
                                                float4* __restrict__ sbox,
                                                float* __restrict__ sarea) {
    const int b = blockIdx.x;
    const int tid = threadIdx.x;
    const int lane = tid & 63;
    const float* __restrict__ xb = x + (size_t)b * NBOX * 6;
    const unsigned long long* __restrict__ segs_b = segs + (size_t)b * NSEG * SEGCAP;

    __shared__ unsigned hist[256];
    __shared__ unsigned binstart[256];   // descending order: count of entries in bins > this one
    __shared__ unsigned bincnt[256];
    __shared__ int sh_selbin;
    __shared__ unsigned segcnt_l[NSEG];
    __shared__ unsigned long long cand[BINCAP];
    __shared__ unsigned long long sortedl[TOPK];

    if (tid < 256) {
        unsigned h = 0;
        #pragma unroll
        for (int sl = 0; sl < 16; ++sl) h += ghist[((size_t)(b * 16 + sl)) * 256 + tid];
        hist[tid] = h;
        bincnt[tid] = 0;
    }
    if (tid < NSEG) segcnt_l[tid] = segcnt[b * NSEG + tid];
    if (tid == 0) sh_selbin = 0;
    sortedl[tid] = 0ull;
    __syncthreads();

    // suffix sums -> binstart + selbin
    if (tid < 64) {
        unsigned c0 = hist[tid*4+0], c1 = hist[tid*4+1];
        unsigned c2 = hist[tid*4+2], c3 = hist[tid*4+3];
        unsigned s3 = c3, s2 = c2 + s3, s1 = c1 + s2, s0 = c0 + s1;
        unsigned suf = s0;
        #pragma unroll
        for (int off = 1; off < 64; off <<= 1) {
            unsigned o = (unsigned)__shfl_down((int)suf, off);
            if (lane + off < 64) suf += o;
        }
        unsigned excl = suf - s0;                 // sum over groups > lane
        binstart[tid*4+0] = excl + s1;
        binstart[tid*4+1] = excl + s2;
        binstart[tid*4+2] = excl + s3;
        binstart[tid*4+3] = excl;
        unsigned S0 = excl+s0, S1 = excl+s1, S2 = excl+s2, S3 = excl+s3;
        if (S0 >= TOPK && S1 < TOPK) sh_selbin = tid*4+0;
        if (S1 >= TOPK && S2 < TOPK) sh_selbin = tid*4+1;
        if (S2 >= TOPK && S3 < TOPK) sh_selbin = tid*4+2;
        if (S3 >= TOPK && excl < TOPK) sh_selbin = tid*4+3;
    }
    __syncthreads();
    const unsigned selbin = (unsigned)sh_selbin;
    const int C = (int)min(binstart[selbin] + hist[selbin], (unsigned)BINCAP);

    // stage: flat sweep of all segment slots, LDS bucket-scatter for bins >= selbin
    for (int idx = tid; idx < NSEG * SEGCAP; idx += 1024) {
        const int seg = idx >> 8;            // /SEGCAP
        const int i = idx & (SEGCAP - 1);
        if (i < (int)segcnt_l[seg]) {
            unsigned long long pk = segs_b[idx];
            unsigned bin = (unsigned)(pk >> 48);
            if (bin >= selbin) {
                unsigned pos = binstart[bin] + atomicAdd(&bincnt[bin], 1u);
                if (pos < BINCAP) cand[pos] = pk;
            }
        }
    }
    __syncthreads();

    // within-bin exact rank (bins disjoint, ordered descending)
    for (int e = tid; e < C; e += 1024) {
        unsigned long long mine = cand[e];
        unsigned bin = (unsigned)(mine >> 48);
        unsigned js = binstart[bin];
        unsigned je = min(js + hist[bin], (unsigned)C);
        int rank = (int)js;
        for (unsigned j = js; j < je; ++j) rank += (cand[j] > mine) ? 1 : 0;
        if (rank < TOPK) sortedl[rank] = mine;
    }
    __syncthreads();

    // epilogue: write sorted keys + gathered boxes/areas
    unsigned long long pk = sortedl[tid];
    sorted_g[(size_t)b * TOPK + tid] = pk;
    int n = (int)(~(unsigned)pk);
    if (n < 0 || n >= NBOX) n = 0;
    float2 p01 = *reinterpret_cast<const float2*>(xb + n * 6);
    float2 p23 = *reinterpret_cast<const float2*>(xb + n * 6 + 2);
    float x1 = p01.x - p23.x * 0.5f, y1 = p01.y - p23.y * 0.5f;
    float x2 = p01.x + p23.x * 0.5f, y2 = p01.y + p23.y * 0.5f;
    sbox[(size_t)b * TOPK + tid] = make_float4(x1, y1, x2, y2);
    sarea[(size_t)b * TOPK + tid] = (x2 - x1) * (y2 - y1);
}

// ================= K4: inline blocked resolve + early-exit at 300 kept + output =================
__global__ __launch_bounds__(1024) void k4_resolve(const unsigned long long* __restrict__ sorted_g,
                                                   const float4* __restrict__ sbox,
                                                   const float* __restrict__ sarea,
                                                   float* __restrict__ out) {
    const int b = blockIdx.x;
    const int tid = threadIdx.x;
    const int lane = tid & 63;
    const int wv = tid >> 6;

    __shared__ float4 bbox[TOPK];
    __shared__ float bar[TOPK];
    __shared__ unsigned long long keptb[16];
    __shared__ int pre[17];
    __shared__ int sh_acc, sh_cut;

    if (tid < 16) keptb[tid] = 0ull;               // chunks past the cutoff stay 0
    if (tid == 0) { sh_acc = 0; sh_cut = 15; }     // default cutoff = last chunk

    const unsigned long long pk = sorted_g[(size_t)b * TOPK + tid];
    bool alive = (pk != 0ull);
    const float4 mybox = sbox[(size_t)b * TOPK + tid];
    const float my_ar = sarea[(size_t)b * TOPK + tid];
    bbox[tid] = mybox;
    bar[tid] = my_ar;
    __syncthreads();

    // intra-chunk suppression mask (pure geometry, parallel)
    const int cbase = tid & ~63;
    unsigned long long my_mask = 0ull;
    #pragma unroll 4
    for (int i = 0; i < 64; ++i) {
        float iou = iou_of(bbox[cbase + i], bar[cbase + i], mybox, my_ar);
        if (i < lane && iou > IOU_T) my_mask |= (1ull << i);
    }

    for (int c = 0; c < 16; ++c) {
        if (wv == c) {
            unsigned long long rem = __ballot(alive);
            unsigned long long kept = 0ull;
            while (rem) {
                int i = __ffsll((long long)rem) - 1;
                unsigned long long bit = 1ull << i;
                kept |= bit;
                unsigned long long row = __ballot((unsigned)((my_mask >> i) & 1ull));
                rem &= ~(row | bit);
            }
            alive = (kept >> lane) & 1ull;
            if (lane == 0) {
                keptb[c] = kept;
                int acc = sh_acc + (int)__popcll(kept);
                sh_acc = acc;
                if (acc >= MAXDET && c < sh_cut) sh_cut = c;   // 300th kept lives in chunk c
            }
        }
        __syncthreads();
        if (c >= sh_cut) break;        // uniform: later chunks cannot affect the first 300 kept
        if (wv > c && alive) {
            unsigned long long k = keptb[c];
            while (k) {
                int i = __ffsll((long long)k) - 1;
                k &= k - 1;
                float iou = iou_of(bbox[c * 64 + i], bar[c * 64 + i], mybox, my_ar);
                if (iou > IOU_T) { alive = false; break; }
            }
        }
    }

    // rank kept entries, write output (keptb[c > cut] == 0 -> ranks past cutoff >= 300)
    if (tid == 0) {
        int acc = 0;
        #pragma unroll
        for (int c = 0; c < 16; ++c) { pre[c] = acc; acc += (int)__popcll(keptb[c]); }
        pre[16] = acc;
    }
    __syncthreads();
    const int total = pre[16];

    float* __restrict__ ob = out + (size_t)b * MAXDET * 6;
    const int rank = pre[wv] + (int)__popcll(keptb[wv] & ((1ull << lane) - 1ull));
    if (alive && wv <= sh_cut && rank < MAXDET) {
        float sc_ = __uint_as_float((unsigned)(pk >> 32) + KEY_BIAS);
        ob[rank * 6 + 0] = mybox.x;
        ob[rank * 6 + 1] = mybox.y;
        ob[rank * 6 + 2] = mybox.z;
        ob[rank * 6 + 3] = mybox.w;
        ob[rank * 6 + 4] = sc_;
        ob[rank * 6 + 5] = 0.0f;
    }
    for (int r = tid; r < MAXDET; r += 1024) {
        if (r >= total) {
            #pragma unroll
            for (int cc = 0; cc < 6; ++cc) ob[r * 6 + cc] = 0.0f;
        }
    }
}

// ================= fallback: single-kernel (used only if ws too small) =================
__global__ __launch_bounds__(1024) void nms_single_kernel(const float* __restrict__ x,
                                                          float* __restrict__ out) {
    const int b = blockIdx.x;
    const int tid = threadIdx.x;
    const int lane = tid & 63;
    const int wv = tid >> 6;
    const float* __restrict__ xb = x + (size_t)b * NBOX * 6;

    __shared__ unsigned hist[256];
    __shared__ int sh_selbin;
    __shared__ unsigned sh_cnt;
    __shared__ unsigned long long cand[BINCAP];
    __shared__ unsigned long long keys[TOPK];
    __shared__ float4 bbox[TOPK];
    __shared__ float bar[TOPK];
    __shared__ float4 lbox[2][64];
    __shared__ float lar[2][64];
    __shared__ int listn[2];
    __shared__ int wcnt[16], wpre[16];
    __shared__ int sh_total;

    if (tid < 256) hist[tid] = 0;
    if (tid == 0) { sh_selbin = 0; sh_cnt = 0; }
    keys[tid] = 0ull;
    __syncthreads();
    for (int n = tid; n < NBOX; n += 1024) {
        float2 oc = *reinterpret_cast<const float2*>(xb + n * 6 + 4);
        float conf = oc.x * oc.y;
        if (conf > CONF_T) atomicAdd(&hist[(__float_as_uint(conf) - KEY_BIAS) >> 16], 1u);
    }
    __syncthreads();
    if (tid < 64) {
        unsigned c0 = hist[tid*4+0], c1 = hist[tid*4+1];
        unsigned c2 = hist[tid*4+2], c3 = hist[tid*4+3];
        unsigned s3 = c3, s2 = c2 + s3, s1 = c1 + s2, s0 = c0 + s1;
        unsigned suf = s0;
        #pragma unroll
        for (int off = 1; off < 64; off <<= 1) {
            unsigned o = (unsigned)__shfl_down((int)suf, off);
            if (lane + off < 64) suf += o;
        }
        unsigned excl = suf - s0;
        unsigned S0 = excl+s0, S1 = excl+s1, S2 = excl+s2, S3 = excl+s3;
        if (S0 >= TOPK && S1 < TOPK) sh_selbin = tid*4+0;
        if (S1 >= TOPK && S2 < TOPK) sh_selbin = tid*4+1;
        if (S2 >= TOPK && S3 < TOPK) sh_selbin = tid*4+2;
        if (S3 >= TOPK && excl < TOPK) sh_selbin = tid*4+3;
    }
    __syncthreads();
    const unsigned selbin = (unsigned)sh_selbin;
    for (int n = tid; n < NBOX; n += 1024) {
        float2 oc = *reinterpret_cast<const float2*>(xb + n * 6 + 4);
        float conf = oc.x * oc.y;
        bool take = false; unsigned key = 0;
        if (conf > CONF_T) {
            key = __float_as_uint(conf) - KEY_BIAS;
            take = ((key >> 16) >= selbin);
        }
        unsigned long long m = __ballot(take);
        unsigned base = 0;
        if (lane == 0 && m) base = atomicAdd(&sh_cnt, (unsigned)__popcll(m));
        base = (unsigned)__shfl((int)base, 0);
        if (take) {
            unsigned pos = base + (unsigned)__popcll(m & ((1ull << lane) - 1ull));
            if (pos < BINCAP)
                cand[pos] = ((unsigned long long)key << 32) | (unsigned)(~(unsigned)n);
        }
    }
    __syncthreads();
    const int C = (int)min(sh_cnt, (unsigned)BINCAP);
    for (int e = tid; e < C; e += 1024) {
        unsigned long long mine = cand[e];
        int rank = 0;
        #pragma unroll 8
        for (int j = 0; j < C; ++j) rank += (cand[j] > mine) ? 1 : 0;
        if (rank < TOPK) keys[rank] = mine;
    }
    __syncthreads();
    unsigned long long kk = keys[tid];
    unsigned key24 = (unsigned)(kk >> 32);
    int n = (int)(~(unsigned)kk);
    bool alive = (kk != 0ull);
    if (n < 0 || n >= NBOX) { n = 0; alive = false; }
    float sc_ = __uint_as_float(key24 + KEY_BIAS);
    float2 p01 = *reinterpret_cast<const float2*>(xb + n * 6);
    float2 p23 = *reinterpret_cast<const float2*>(xb + n * 6 + 2);
    float x1 = p01.x - p23.x * 0.5f, y1 = p01.y - p23.y * 0.5f;
    float x2 = p01.x + p23.x * 0.5f, y2 = p01.y + p23.y * 0.5f;
    float4 mybox = make_float4(x1, y1, x2, y2);
    float my_ar = (x2 - x1) * (y2 - y1);
    bbox[tid] = mybox;
    bar[tid] = my_ar;
    __syncthreads();
    const int cbase = tid & ~63;
    unsigned long long my_mask = 0ull;
    #pragma unroll 4
    for (int i = 0; i < 64; ++i) {
        float iou = iou_of(bbox[cbase + i], bar[cbase + i], mybox, my_ar);
        if (i < lane && iou > IOU_T) my_mask |= (1ull << i);
    }
    for (int c = 0; c < 16; ++c) {
        if (c > 0 && wv >= c && alive) {
            const int pb = (c - 1) & 1;
            const int m = listn[pb];
            bool sup = false;
            #pragma unroll 2
            for (int t = 0; t < m; ++t) {
                float iou = iou_of(lbox[pb][t], lar[pb][t], mybox, my_ar);
                sup = sup || (iou > IOU_T);
            }
            alive = !sup;
        }
        if (wv == c) {
            unsigned long long rem = __ballot(alive);
            unsigned long long kept = 0ull;
            while (rem) {
                int i = __ffsll((long long)rem) - 1;
                unsigned long long bit = 1ull << i;
                kept |= bit;
                unsigned long long row = __ballot((unsigned)((my_mask >> i) & 1ull));
                rem &= ~(row | bit);
            }
            alive = (kept >> lane) & 1ull;
            int nk = __popcll(kept);
            int rk = __popcll(kept & ((1ull << lane) - 1ull));
            if (alive) { lbox[c & 1][rk] = mybox; lar[c & 1][rk] = my_ar; }
            if (lane == 0) listn[c & 1] = nk;
        }
        __syncthreads();
    }
    unsigned long long m = __ballot(alive);
    if (lane == 0) wcnt[wv] = __popcll(m);
    __syncthreads();
    if (tid == 0) {
        int acc = 0;
        for (int w2 = 0; w2 < 16; ++w2) { wpre[w2] = acc; acc += wcnt[w2]; }
        sh_total = acc;
    }
    __syncthreads();
    const int rank = wpre[wv] + (int)__popcll(m & ((1ull << lane) - 1ull));
    const int total = sh_total;
    float* __restrict__ ob = out + (size_t)b * MAXDET * 6;
    if (alive && rank < MAXDET) {
        ob[rank * 6 + 0] = mybox.x;
        ob[rank * 6 + 1] = mybox.y;
        ob[rank * 6 + 2] = mybox.z;
        ob[rank * 6 + 3] = mybox.w;
        ob[rank * 6 + 4] = sc_;
        ob[rank * 6 + 5] = 0.0f;
    }
    for (int r = tid; r < MAXDET; r += 1024) {
        if (r >= total) {
            #pragma unroll
            for (int cc = 0; cc < 6; ++cc) ob[r * 6 + cc] = 0.0f;
        }
    }
}

extern "C" void kernel_launch(void* const* d_in, const int* in_sizes, int n_in,
                              void* d_out, int out_size, void* d_ws, size_t ws_size,
                              hipStream_t stream) {
    const float* x = (const float*)d_in[0];
    float* out = (float*)d_out;
    if (ws_size >= (size_t)WS_NEED) {
        char* ws = (char*)d_ws;
        unsigned long long* segs   = (unsigned long long*)(ws + SEGS_OFF);
        unsigned* segcnt           = (unsigned*)(ws + SEGCNT_OFF);
        unsigned* ghist            = (unsigned*)(ws + GHIST_OFF);
        unsigned long long* sorted = (unsigned long long*)(ws + SORTED_OFF);
        float4* sbox               = (float4*)(ws + SBOX_OFF);
        float* sarea               = (float*)(ws + SAREA_OFF);
        hipLaunchKernelGGL(k1_extract, dim3(512), dim3(256), 0, stream,
                           x, segs, segcnt, ghist);
        hipLaunchKernelGGL(k2_sort, dim3(BATCH), dim3(1024), 0, stream,
                           x, segs, segcnt, ghist, sorted, sbox, sarea);
        hipLaunchKernelGGL(k4_resolve, dim3(BATCH), dim3(1024), 0, stream,
                           sorted, sbox, sarea, out);
    } else {
        hipLaunchKernelGGL(nms_single_kernel, dim3(BATCH), dim3(1024), 0, stream, x, out);
    }
}

// Round 13
// 57.252 us; speedup vs baseline: 1.7311x; 1.7311x over previous
//
#include <hip/hip_runtime.h>
#include <stdint.h>

#define NBOX 25200
#define BATCH 32
#define TOPK 1024
#define MAXDET 300
#define BINCAP 2048
#define SEGCAP 256
#define NSEG 64
#define CONF_T 0.25f
#define IOU_T 0.45f
#define KEY_BIAS 0x3E800001u   // conf > 0.25 => bits(conf) >= 0x3E800001; key in [0, 0x00FFFFFF]

// ---- workspace layout (bytes) ----
#define SEGS_OFF   0u            // [32][64][256] u64  = 4194304
#define SEGCNT_OFF 4194304u      // [32][64] u32       = 8192
#define GHIST_OFF  4202496u      // [32][16][256] u32  = 524288
#define SORTED_OFF 4726784u      // [32][1024] u64     = 262144
#define SBOX_OFF   4988928u      // [32][1024] float4  = 524288
#define SAREA_OFF  5513216u      // [32][1024] f32     = 131072
#define MASKS_OFF  5644288u      // [32][16][16][64] u64 = 2097152  (b, jc, ic, j)
#define WS_NEED    7741440u

__device__ __forceinline__ float iou_of(float4 a, float ar_a, float4 bq, float ar_b) {
    float xx1 = fmaxf(a.x, bq.x);
    float yy1 = fmaxf(a.y, bq.y);
    float xx2 = fminf(a.z, bq.z);
    float yy2 = fminf(a.w, bq.w);
    float iw = fmaxf(xx2 - xx1, 0.0f);
    float ih = fmaxf(yy2 - yy1, 0.0f);
    float inter = iw * ih;
    return inter / (ar_a + ar_b - inter + 1e-9f);
}

// ================= K1: per-wave segment extract (512 blocks, 2/CU; no zeroing, no global atomics) ===
__global__ __launch_bounds__(256) void k1_extract(const float* __restrict__ x,
                                                  unsigned long long* __restrict__ segs,
                                                  unsigned* __restrict__ segcnt,
                                                  unsigned* __restrict__ ghist) {
    const int blk = blockIdx.x;          // 512 = 32 batches * 16 slices
    const int b = blk >> 4;
    const int sl = blk & 15;
    const int tid = threadIdx.x;
    const int lane = tid & 63;
    const int wv = tid >> 6;
    const int seg = sl * 4 + wv;         // 0..63
    const float* __restrict__ xb = x + (size_t)b * NBOX * 6;
    unsigned long long* __restrict__ sb = segs + ((size_t)b * NSEG + seg) * SEGCAP;

    __shared__ unsigned hist[256];
    hist[tid] = 0;
    __syncthreads();

    const int n0 = (seg * NBOX) / NSEG;
    const int n1 = ((seg + 1) * NBOX) / NSEG;
    unsigned base = 0;
    const unsigned long long lmask = (1ull << lane) - 1ull;
    #pragma unroll 2
    for (int n = n0 + lane; n < n1; n += 64) {
        float2 oc = *reinterpret_cast<const float2*>(xb + n * 6 + 4);
        float conf = oc.x * oc.y;
        bool take = conf > CONF_T;
        unsigned key = 0;
        if (take) {
            key = __float_as_uint(conf) - KEY_BIAS;
            atomicAdd(&hist[min(key >> 16, 255u)], 1u);
        }
        unsigned long long m = __ballot(take);
        if (take) {
            unsigned pos = base + (unsigned)__popcll(m & lmask);
            if (pos < SEGCAP)
                sb[pos] = ((unsigned long long)key << 32) | (unsigned)(~(unsigned)n);
        }
        base += (unsigned)__popcll(m);
    }
    if (lane == 0) segcnt[b * NSEG + seg] = min(base, (unsigned)SEGCAP);
    __syncthreads();
    ghist[(size_t)blk * 256 + tid] = hist[tid];
}

// ================= K2: selbin + LDS bucket-scatter + within-bin rank + gather =================
__global__ __launch_bounds__(1024) void k2_sort(const float* __restrict__ x,
                                                const unsigned long long* __restrict__ segs,
                                                const unsigned* __restrict__ segcnt,
                                                const unsigned* __restrict__ ghist,
                                                unsigned long long* __restrict__ sorted_g,
                                                float4* __restrict__ sbox,
                                                float* __restrict__ sarea) {
    const int b = blockIdx.x;
    const int tid = threadIdx.x;
    const int lane = tid & 63;
    const float* __restrict__ xb = x + (size_t)b * NBOX * 6;
    const unsigned long long* __restrict__ segs_b = segs + (size_t)b * NSEG * SEGCAP;

    __shared__ unsigned hist[256];
    __shared__ unsigned binstart[256];   // descending order: count of entries in bins > this one
    __shared__ unsigned bincnt[256];
    __shared__ int sh_selbin;
    __shared__ unsigned segcnt_l[NSEG];
    __shared__ unsigned long long cand[BINCAP];
    __shared__ unsigned long long sortedl[TOPK];

    if (tid < 256) {
        unsigned h = 0;
        #pragma unroll
        for (int sl = 0; sl < 16; ++sl) h += ghist[((size_t)(b * 16 + sl)) * 256 + tid];
        hist[tid] = h;
        bincnt[tid] = 0;
    }
    if (tid < NSEG) segcnt_l[tid] = segcnt[b * NSEG + tid];
    if (tid == 0) sh_selbin = 0;
    sortedl[tid] = 0ull;
    __syncthreads();

    // suffix sums -> binstart + selbin
    if (tid < 64) {
        unsigned c0 = hist[tid*4+0], c1 = hist[tid*4+1];
        unsigned c2 = hist[tid*4+2], c3 = hist[tid*4+3];
        unsigned s3 = c3, s2 = c2 + s3, s1 = c1 + s2, s0 = c0 + s1;
        unsigned suf = s0;
        #pragma unroll
        for (int off = 1; off < 64; off <<= 1) {
            unsigned o = (unsigned)__shfl_down((int)suf, off);
            if (lane + off < 64) suf += o;
        }
        unsigned excl = suf - s0;                 // sum over groups > lane
        binstart[tid*4+0] = excl + s1;
        binstart[tid*4+1] = excl + s2;
        binstart[tid*4+2] = excl + s3;
        binstart[tid*4+3] = excl;
        unsigned S0 = excl+s0, S1 = excl+s1, S2 = excl+s2, S3 = excl+s3;
        if (S0 >= TOPK && S1 < TOPK) sh_selbin = tid*4+0;
        if (S1 >= TOPK && S2 < TOPK) sh_selbin = tid*4+1;
        if (S2 >= TOPK && S3 < TOPK) sh_selbin = tid*4+2;
        if (S3 >= TOPK && excl < TOPK) sh_selbin = tid*4+3;
    }
    __syncthreads();
    const unsigned selbin = (unsigned)sh_selbin;
    const int C = (int)min(binstart[selbin] + hist[selbin], (unsigned)BINCAP);

    // stage: flat sweep of all segment slots, LDS bucket-scatter for bins >= selbin
    for (int idx = tid; idx < NSEG * SEGCAP; idx += 1024) {
        const int seg = idx >> 8;            // /SEGCAP
        const int i = idx & (SEGCAP - 1);
        if (i < (int)segcnt_l[seg]) {
            unsigned long long pk = segs_b[idx];
            unsigned bin = (unsigned)(pk >> 48);
            if (bin >= selbin) {
                unsigned pos = binstart[bin] + atomicAdd(&bincnt[bin], 1u);
                if (pos < BINCAP) cand[pos] = pk;
            }
        }
    }
    __syncthreads();

    // within-bin exact rank (bins disjoint, ordered descending)
    for (int e = tid; e < C; e += 1024) {
        unsigned long long mine = cand[e];
        unsigned bin = (unsigned)(mine >> 48);
        unsigned js = binstart[bin];
        unsigned je = min(js + hist[bin], (unsigned)C);
        int rank = (int)js;
        for (unsigned j = js; j < je; ++j) rank += (cand[j] > mine) ? 1 : 0;
        if (rank < TOPK) sortedl[rank] = mine;
    }
    __syncthreads();

    // epilogue: write sorted keys + gathered boxes/areas
    unsigned long long pk = sortedl[tid];
    sorted_g[(size_t)b * TOPK + tid] = pk;
    int n = (int)(~(unsigned)pk);
    if (n < 0 || n >= NBOX) n = 0;
    float2 p01 = *reinterpret_cast<const float2*>(xb + n * 6);
    float2 p23 = *reinterpret_cast<const float2*>(xb + n * 6 + 2);
    float x1 = p01.x - p23.x * 0.5f, y1 = p01.y - p23.y * 0.5f;
    float x2 = p01.x + p23.x * 0.5f, y2 = p01.y + p23.y * 0.5f;
    sbox[(size_t)b * TOPK + tid] = make_float4(x1, y1, x2, y2);
    sarea[(size_t)b * TOPK + tid] = (x2 - x1) * (y2 - y1);
}

// ================= K3: pairwise chunk suppression masks (4 pairs/block, full chip) =================
__global__ __launch_bounds__(256) void k3_masks(const float4* __restrict__ sbox,
                                                const float* __restrict__ sarea,
                                                unsigned long long* __restrict__ masks) {
    const int b = blockIdx.y;
    const int wv = threadIdx.x >> 6;
    const int j = threadIdx.x & 63;
    const int p = blockIdx.x * 4 + wv;          // 0..135, ic <= jc

    int jc = (int)((sqrtf(8.0f * (float)p + 1.0f) - 1.0f) * 0.5f);
    while ((jc + 1) * (jc + 2) / 2 <= p) ++jc;
    while (jc * (jc + 1) / 2 > p) --jc;
    const int ic = p - jc * (jc + 1) / 2;

    __shared__ float4 ibox[4][64];
    __shared__ float iar[4][64];
    ibox[wv][j] = sbox[(size_t)b * TOPK + ic * 64 + j];
    iar[wv][j]  = sarea[(size_t)b * TOPK + ic * 64 + j];
    const float4 mb = sbox[(size_t)b * TOPK + jc * 64 + j];
    const float ma  = sarea[(size_t)b * TOPK + jc * 64 + j];
    __syncthreads();

    unsigned long long w = 0ull;
    #pragma unroll 4
    for (int i = 0; i < 64; ++i) {
        float iou = iou_of(ibox[wv][i], iar[wv][i], mb, ma);
        bool bit = (iou > IOU_T) && (ic != jc || i < j);
        if (bit) w |= (1ull << i);
    }
    masks[(((size_t)b * 16 + jc) * 16 + ic) * 64 + j] = w;   // lane-coalesced
}

// ================= K4: serial resolve (bit-ops only) + early-exit at 300 kept + output =================
__global__ __launch_bounds__(1024) void k4_resolve(const unsigned long long* __restrict__ sorted_g,
                                                   const float4* __restrict__ sbox,
                                                   const unsigned long long* __restrict__ masks,
                                                   float* __restrict__ out) {
    const int b = blockIdx.x;
    const int tid = threadIdx.x;
    const int lane = tid & 63;
    const int wv = tid >> 6;

    __shared__ unsigned long long keptb[16];
    __shared__ int pre[17];
    __shared__ int sh_acc, sh_cut;

    if (tid < 16) keptb[tid] = 0ull;               // chunks past the cutoff stay 0
    if (tid == 0) { sh_acc = 0; sh_cut = 15; }     // default cutoff = last chunk

    const unsigned long long pk = sorted_g[(size_t)b * TOPK + tid];
    bool alive = (pk != 0ull);

    // prefetch this thread's 16 chunk-masks (coalesced; entries with c > wv are unused garbage)
    unsigned long long wcs[16];
    #pragma unroll
    for (int c = 0; c < 16; ++c)
        wcs[c] = masks[(((size_t)b * 16 + wv) * 16 + c) * 64 + lane];

    #pragma unroll
    for (int c = 0; c < 16; ++c) {
        if (wv == c) {
            unsigned long long rem = __ballot(alive);
            unsigned long long kept = 0ull;
            while (rem) {
                int i = __ffsll((long long)rem) - 1;
                unsigned long long bit = 1ull << i;
                kept |= bit;
                unsigned long long row = __ballot((unsigned)((wcs[c] >> i) & 1ull));
                rem &= ~(row | bit);
            }
            alive = (kept >> lane) & 1ull;
            if (lane == 0) {
                keptb[c] = kept;
                int acc = sh_acc + (int)__popcll(kept);
                sh_acc = acc;
                if (acc >= MAXDET && c < sh_cut) sh_cut = c;   // 300th kept lives in chunk c
            }
        }
        __syncthreads();
        if (c >= sh_cut) break;        // uniform: later chunks cannot affect the first 300 kept
        if (wv > c && alive && (wcs[c] & keptb[c])) alive = false;
    }

    // rank kept entries, write output (keptb[c > cut] == 0 -> ranks past cutoff >= 300)
    if (tid == 0) {
        int acc = 0;
        #pragma unroll
        for (int c = 0; c < 16; ++c) { pre[c] = acc; acc += (int)__popcll(keptb[c]); }
        pre[16] = acc;
    }
    __syncthreads();
    const int total = pre[16];

    float* __restrict__ ob = out + (size_t)b * MAXDET * 6;
    const int rank = pre[wv] + (int)__popcll(keptb[wv] & ((1ull << lane) - 1ull));
    if (alive && wv <= sh_cut && rank < MAXDET) {
        float4 bx = sbox[(size_t)b * TOPK + tid];
        float sc_ = __uint_as_float((unsigned)(pk >> 32) + KEY_BIAS);
        ob[rank * 6 + 0] = bx.x;
        ob[rank * 6 + 1] = bx.y;
        ob[rank * 6 + 2] = bx.z;
        ob[rank * 6 + 3] = bx.w;
        ob[rank * 6 + 4] = sc_;
        ob[rank * 6 + 5] = 0.0f;
    }
    for (int r = tid; r < MAXDET; r += 1024) {
        if (r >= total) {
            #pragma unroll
            for (int cc = 0; cc < 6; ++cc) ob[r * 6 + cc] = 0.0f;
        }
    }
}

// ================= fallback: single-kernel (used only if ws too small) =================
__global__ __launch_bounds__(1024) void nms_single_kernel(const float* __restrict__ x,
                                                          float* __restrict__ out) {
    const int b = blockIdx.x;
    const int tid = threadIdx.x;
    const int lane = tid & 63;
    const int wv = tid >> 6;
    const float* __restrict__ xb = x + (size_t)b * NBOX * 6;

    __shared__ unsigned hist[256];
    __shared__ int sh_selbin;
    __shared__ unsigned sh_cnt;
    __shared__ unsigned long long cand[BINCAP];
    __shared__ unsigned long long keys[TOPK];
    __shared__ float4 bbox[TOPK];
    __shared__ float bar[TOPK];
    __shared__ float4 lbox[2][64];
    __shared__ float lar[2][64];
    __shared__ int listn[2];
    __shared__ int wcnt[16], wpre[16];
    __shared__ int sh_total;

    if (tid < 256) hist[tid] = 0;
    if (tid == 0) { sh_selbin = 0; sh_cnt = 0; }
    keys[tid] = 0ull;
    __syncthreads();
    for (int n = tid; n < NBOX; n += 1024) {
        float2 oc = *reinterpret_cast<const float2*>(xb + n * 6 + 4);
        float conf = oc.x * oc.y;
        if (conf > CONF_T) atomicAdd(&hist[(__float_as_uint(conf) - KEY_BIAS) >> 16], 1u);
    }
    __syncthreads();
    if (tid < 64) {
        unsigned c0 = hist[tid*4+0], c1 = hist[tid*4+1];
        unsigned c2 = hist[tid*4+2], c3 = hist[tid*4+3];
        unsigned s3 = c3, s2 = c2 + s3, s1 = c1 + s2, s0 = c0 + s1;
        unsigned suf = s0;
        #pragma unroll
        for (int off = 1; off < 64; off <<= 1) {
            unsigned o = (unsigned)__shfl_down((int)suf, off);
            if (lane + off < 64) suf += o;
        }
        unsigned excl = suf - s0;
        unsigned S0 = excl+s0, S1 = excl+s1, S2 = excl+s2, S3 = excl+s3;
        if (S0 >= TOPK && S1 < TOPK) sh_selbin = tid*4+0;
        if (S1 >= TOPK && S2 < TOPK) sh_selbin = tid*4+1;
        if (S2 >= TOPK && S3 < TOPK) sh_selbin = tid*4+2;
        if (S3 >= TOPK && excl < TOPK) sh_selbin = tid*4+3;
    }
    __syncthreads();
    const unsigned selbin = (unsigned)sh_selbin;
    for (int n = tid; n < NBOX; n += 1024) {
        float2 oc = *reinterpret_cast<const float2*>(xb + n * 6 + 4);
        float conf = oc.x * oc.y;
        bool take = false; unsigned key = 0;
        if (conf > CONF_T) {
            key = __float_as_uint(conf) - KEY_BIAS;
            take = ((key >> 16) >= selbin);
        }
        unsigned long long m = __ballot(take);
        unsigned base = 0;
        if (lane == 0 && m) base = atomicAdd(&sh_cnt, (unsigned)__popcll(m));
        base = (unsigned)__shfl((int)base, 0);
        if (take) {
            unsigned pos = base + (unsigned)__popcll(m & ((1ull << lane) - 1ull));
            if (pos < BINCAP)
                cand[pos] = ((unsigned long long)key << 32) | (unsigned)(~(unsigned)n);
        }
    }
    __syncthreads();
    const int C = (int)min(sh_cnt, (unsigned)BINCAP);
    for (int e = tid; e < C; e += 1024) {
        unsigned long long mine = cand[e];
        int rank = 0;
        #pragma unroll 8
        for (int j = 0; j < C; ++j) rank += (cand[j] > mine) ? 1 : 0;
        if (rank < TOPK) keys[rank] = mine;
    }
    __syncthreads();
    unsigned long long kk = keys[tid];
    unsigned key24 = (unsigned)(kk >> 32);
    int n = (int)(~(unsigned)kk);
    bool alive = (kk != 0ull);
    if (n < 0 || n >= NBOX) { n = 0; alive = false; }
    float sc_ = __uint_as_float(key24 + KEY_BIAS);
    float2 p01 = *reinterpret_cast<const float2*>(xb + n * 6);
    float2 p23 = *reinterpret_cast<const float2*>(xb + n * 6 + 2);
    float x1 = p01.x - p23.x * 0.5f, y1 = p01.y - p23.y * 0.5f;
    float x2 = p01.x + p23.x * 0.5f, y2 = p01.y + p23.y * 0.5f;
    float4 mybox = make_float4(x1, y1, x2, y2);
    float my_ar = (x2 - x1) * (y2 - y1);
    bbox[tid] = mybox;
    bar[tid] = my_ar;
    __syncthreads();
    const int cbase = tid & ~63;
    unsigned long long my_mask = 0ull;
    #pragma unroll 4
    for (int i = 0; i < 64; ++i) {
        float iou = iou_of(bbox[cbase + i], bar[cbase + i], mybox, my_ar);
        if (i < lane && iou > IOU_T) my_mask |= (1ull << i);
    }
    for (int c = 0; c < 16; ++c) {
        if (c > 0 && wv >= c && alive) {
            const int pb = (c - 1) & 1;
            const int m = listn[pb];
            bool sup = false;
            #pragma unroll 2
            for (int t = 0; t < m; ++t) {
                float iou = iou_of(lbox[pb][t], lar[pb][t], mybox, my_ar);
                sup = sup || (iou > IOU_T);
            }
            alive = !sup;
        }
        if (wv == c) {
            unsigned long long rem = __ballot(alive);
            unsigned long long kept = 0ull;
            while (rem) {
                int i = __ffsll((long long)rem) - 1;
                unsigned long long bit = 1ull << i;
                kept |= bit;
                unsigned long long row = __ballot((unsigned)((my_mask >> i) & 1ull));
                rem &= ~(row | bit);
            }
            alive = (kept >> lane) & 1ull;
            int nk = __popcll(kept);
            int rk = __popcll(kept & ((1ull << lane) - 1ull));
            if (alive) { lbox[c & 1][rk] = mybox; lar[c & 1][rk] = my_ar; }
            if (lane == 0) listn[c & 1] = nk;
        }
        __syncthreads();
    }
    unsigned long long m = __ballot(alive);
    if (lane == 0) wcnt[wv] = __popcll(m);
    __syncthreads();
    if (tid == 0) {
        int acc = 0;
        for (int w2 = 0; w2 < 16; ++w2) { wpre[w2] = acc; acc += wcnt[w2]; }
        sh_total = acc;
    }
    __syncthreads();
    const int rank = wpre[wv] + (int)__popcll(m & ((1ull << lane) - 1ull));
    const int total = sh_total;
    float* __restrict__ ob = out + (size_t)b * MAXDET * 6;
    if (alive && rank < MAXDET) {
        ob[rank * 6 + 0] = mybox.x;
        ob[rank * 6 + 1] = mybox.y;
        ob[rank * 6 + 2] = mybox.z;
        ob[rank * 6 + 3] = mybox.w;
        ob[rank * 6 + 4] = sc_;
        ob[rank * 6 + 5] = 0.0f;
    }
    for (int r = tid; r < MAXDET; r += 1024) {
        if (r >= total) {
            #pragma unroll
            for (int cc = 0; cc < 6; ++cc) ob[r * 6 + cc] = 0.0f;
        }
    }
}

extern "C" void kernel_launch(void* const* d_in, const int* in_sizes, int n_in,
                              void* d_out, int out_size, void* d_ws, size_t ws_size,
                              hipStream_t stream) {
    const float* x = (const float*)d_in[0];
    float* out = (float*)d_out;
    if (ws_size >= (size_t)WS_NEED) {
        char* ws = (char*)d_ws;
        unsigned long long* segs   = (unsigned long long*)(ws + SEGS_OFF);
        unsigned* segcnt           = (unsigned*)(ws + SEGCNT_OFF);
        unsigned* ghist            = (unsigned*)(ws + GHIST_OFF);
        unsigned long long* sorted = (unsigned long long*)(ws + SORTED_OFF);
        float4* sbox               = (float4*)(ws + SBOX_OFF);
        float* sarea               = (float*)(ws + SAREA_OFF);
        unsigned long long* masks  = (unsigned long long*)(ws + MASKS_OFF);
        hipLaunchKernelGGL(k1_extract, dim3(512), dim3(256), 0, stream,
                           x, segs, segcnt, ghist);
        hipLaunchKernelGGL(k2_sort, dim3(BATCH), dim3(1024), 0, stream,
                           x, segs, segcnt, ghist, sorted, sbox, sarea);
        hipLaunchKernelGGL(k3_masks, dim3(34, BATCH), dim3(256), 0, stream,
                           sbox, sarea, masks);
        hipLaunchKernelGGL(k4_resolve, dim3(BATCH), dim3(1024), 0, stream,
                           sorted, sbox, masks, out);
    } else {
        hipLaunchKernelGGL(nms_single_kernel, dim3(BATCH), dim3(1024), 0, stream, x, out);
    }
}